// Round 2
// 1261.430 us; speedup vs baseline: 1.0507x; 1.0507x over previous
//
#include <hip/hip_runtime.h>
#include <hip/hip_bf16.h>

typedef __hip_bfloat16 bf16;
typedef float f32x4 __attribute__((ext_vector_type(4)));
typedef short s16x8 __attribute__((ext_vector_type(8)));
typedef unsigned short u16x4 __attribute__((ext_vector_type(4)));

#define SCALER_F 0.17677669529663687f  // 1/sqrt(32)

// ---------------------------------------------------------------------------
// prep_kernel: ONE launch for all input conversions.
//  blocks [0, 33920): memory [131072,265] f32 -> [131072,288] bf16, flat f32x4
//  blocks [33920, 45696): zero-pad cols 265..287 of memb
//  blocks [45696, 51584): weight transposes src[K][N] f32 -> dst[N][Kpad] bf16
//  block  51584: kv bias concat
// ---------------------------------------------------------------------------
#define MEM_BLKS 33920   // 131072*265/4/256
#define PAD_BLKS 11776   // 131072*23/256

__global__ __launch_bounds__(256) void prep_kernel(
    const float* __restrict__ mem, bf16* __restrict__ mb,
    const float* __restrict__ Wq, const float* __restrict__ Wk,
    const float* __restrict__ Wv, const float* __restrict__ Wf,
    const float* __restrict__ W1, const float* __restrict__ W2,
    const float* __restrict__ Wp1, const float* __restrict__ Wp2,
    const float* __restrict__ bk, const float* __restrict__ bv,
    bf16* __restrict__ wqT, bf16* __restrict__ wkvT, bf16* __restrict__ wfT,
    bf16* __restrict__ w1T, bf16* __restrict__ w2T,
    bf16* __restrict__ wp1T, bf16* __restrict__ wp2T,
    float* __restrict__ kvbias) {
  int bid = blockIdx.x;
  const int t = threadIdx.x;
  if (bid < MEM_BLKS) {
    const long g4 = (long)bid * 256 + t;
    const f32x4 v = *(const f32x4*)(mem + g4 * 4);
    long g = g4 * 4;
    unsigned r = (unsigned)(g / 265);
    unsigned c = (unsigned)(g - (long)r * 265);
#pragma unroll
    for (int j = 0; j < 4; j++) {
      mb[(long)r * 288 + c] = __float2bfloat16(v[j]);
      if (++c == 265) { c = 0; r++; }
    }
    return;
  }
  bid -= MEM_BLKS;
  if (bid < PAD_BLKS) {
    const int p = bid * 256 + t;
    const int r = p / 23, c = 265 + p % 23;
    mb[(long)r * 288 + c] = __float2bfloat16(0.f);
    return;
  }
  bid -= PAD_BLKS;
  const float* src; bf16* dst; int K, N, n, Kpad;
  if (bid < 1024) {
    const int l = bid >> 9, pt = (bid >> 8) & 1; n = bid & 255;
    src = (pt ? Wv : Wk) + (long)l * 265 * 256;
    dst = wkvT + (long)l * 512 * 288 + (long)pt * 256 * 288;
    K = 265; N = 256; Kpad = 288;
  } else if (bid < 1536) {
    const int i2 = bid - 1024, l = i2 >> 8; n = i2 & 255;
    src = Wq + (long)l * 65536; dst = wqT + (long)l * 65536;
    K = 256; N = 256; Kpad = 256;
  } else if (bid < 2048) {
    const int i2 = bid - 1536, l = i2 >> 8; n = i2 & 255;
    src = Wf + (long)l * 65536; dst = wfT + (long)l * 65536;
    K = 256; N = 256; Kpad = 256;
  } else if (bid < 4096) {
    const int i2 = bid - 2048, l = i2 >> 10; n = i2 & 1023;
    src = W1 + (long)l * 262144; dst = w1T + (long)l * 262144;
    K = 256; N = 1024; Kpad = 256;
  } else if (bid < 4608) {
    const int i2 = bid - 4096, l = i2 >> 8; n = i2 & 255;
    src = W2 + (long)l * 262144; dst = w2T + (long)l * 262144;
    K = 1024; N = 256; Kpad = 1024;
  } else if (bid < 5632) {
    n = bid - 4608; src = Wp1; dst = wp1T; K = 256; N = 1024; Kpad = 256;
  } else if (bid < 5888) {
    n = bid - 5632; src = Wp2; dst = wp2T; K = 1024; N = 256; Kpad = 1024;
  } else {
    for (int i = t; i < 1024; i += 256) {
      const int l = i >> 9, c = i & 511;
      kvbias[i] = (c < 256) ? bk[l * 256 + c] : bv[l * 256 + c - 256];
    }
    return;
  }
  for (int k = t; k < Kpad; k += 256)
    dst[(long)n * Kpad + k] = __float2bfloat16(k < K ? src[(long)k * N + n] : 0.f);
}

// ---------------------------------------------------------------------------
// Pool: z[n,c] = mean over 7x7 of features[n,c,:,:]; also bf16 copy.
// float4 staging (3136 granules/block).
// ---------------------------------------------------------------------------
__global__ __launch_bounds__(256) void pool_kernel(
    const float* __restrict__ feat, float* __restrict__ z, bf16* __restrict__ zb) {
  __shared__ float ls[12544];
  const int n = blockIdx.x, t = threadIdx.x;
  const f32x4* f4 = (const f32x4*)(feat + (long)n * 12544);
#pragma unroll
  for (int i = 0; i < 12; i++) {
    const int e = i * 256 + t;
    *(f32x4*)&ls[e * 4] = f4[e];
  }
  if (t < 64) {
    const int e = 3072 + t;
    *(f32x4*)&ls[e * 4] = f4[e];
  }
  __syncthreads();
  float s = 0.f;
  const float* r = ls + t * 49;
#pragma unroll
  for (int i = 0; i < 49; i++) s += r[i];
  s *= (1.f / 49.f);
  z[n * 256 + t] = s;
  zb[n * 256 + t] = __float2bfloat16(s);
}

// ---------------------------------------------------------------------------
// bf16 MFMA GEMM: C[M,N] = op(A[M,K] @ B[K,N] + bias) * scale, Bt[N][K] input.
// Tile 128x128, BK=32, 256 thr / 4 waves, 4x4 x mfma_16x16x32 per wave.
// SWAPPED-OPERAND epilogue: mfma(bfr, af) puts 4 consecutive C-columns of one
// row in each lane -> one ushort4/float4 store per fragment (16 stores/thread
// instead of 64 scalar 2B stores).
// ---------------------------------------------------------------------------
__global__ __launch_bounds__(256, 2) void gemm_bt(
    const bf16* __restrict__ A, const bf16* __restrict__ Bt,
    const float* __restrict__ bias, float* __restrict__ Cf, bf16* __restrict__ Cb,
    int K, int lda, int ldb, int ldc, float scale, int relu) {
  __shared__ bf16 Als[128 * 32];
  __shared__ bf16 Bls[128 * 32];
  const int m0 = blockIdx.x * 128;
  const int n0 = blockIdx.y * 128;
  const int t = threadIdx.x;
  const int w = t >> 6, lane = t & 63;
  const int rw = (w >> 1) * 64, cw = (w & 1) * 64;
  const int l15 = lane & 15, quad = lane >> 4;

  f32x4 zero4 = {0.f, 0.f, 0.f, 0.f};
  f32x4 acc[4][4];
#pragma unroll
  for (int i = 0; i < 4; i++)
#pragma unroll
    for (int j = 0; j < 4; j++) acc[i][j] = zero4;

  const bf16* Ab = A + (long)m0 * lda;
  const bf16* Bb = Bt + (long)n0 * ldb;
  const int r1 = t >> 2, s1 = t & 3;

  for (int k0 = 0; k0 < K; k0 += 32) {
    __syncthreads();
    __builtin_amdgcn_global_load_lds(
        (const __attribute__((address_space(1))) void*)(Ab + (long)r1 * lda + k0 + s1 * 8),
        (__attribute__((address_space(3))) void*)(Als + t * 8), 16, 0, 0);
    __builtin_amdgcn_global_load_lds(
        (const __attribute__((address_space(1))) void*)(Ab + (long)(r1 + 64) * lda + k0 + s1 * 8),
        (__attribute__((address_space(3))) void*)(Als + 2048 + t * 8), 16, 0, 0);
    __builtin_amdgcn_global_load_lds(
        (const __attribute__((address_space(1))) void*)(Bb + (long)r1 * ldb + k0 + s1 * 8),
        (__attribute__((address_space(3))) void*)(Bls + t * 8), 16, 0, 0);
    __builtin_amdgcn_global_load_lds(
        (const __attribute__((address_space(1))) void*)(Bb + (long)(r1 + 64) * ldb + k0 + s1 * 8),
        (__attribute__((address_space(3))) void*)(Bls + 2048 + t * 8), 16, 0, 0);
    __syncthreads();

    s16x8 af[4], bfr[4];
#pragma unroll
    for (int i = 0; i < 4; i++) {
      af[i]  = *(const s16x8*)(Als + (rw + i * 16 + l15) * 32 + quad * 8);
      bfr[i] = *(const s16x8*)(Bls + (cw + i * 16 + l15) * 32 + quad * 8);
    }
#pragma unroll
    for (int i = 0; i < 4; i++)
#pragma unroll
      for (int j = 0; j < 4; j++)
        acc[i][j] = __builtin_amdgcn_mfma_f32_16x16x32_bf16(bfr[j], af[i], acc[i][j], 0, 0, 0);
  }

  // Swapped C/D layout: C-row = rw+i*16+(lane&15), C-col = cw+j*16+(lane>>4)*4+r
#pragma unroll
  for (int i = 0; i < 4; i++) {
    const long rb = (long)(m0 + rw + i * 16 + l15) * ldc;
#pragma unroll
    for (int j = 0; j < 4; j++) {
      const int colb = n0 + cw + j * 16 + quad * 4;
      f32x4 bv4 = {0.f, 0.f, 0.f, 0.f};
      if (bias) bv4 = *(const f32x4*)(bias + colb);
      f32x4 v;
#pragma unroll
      for (int r = 0; r < 4; r++) {
        float x = (acc[i][j][r] + bv4[r]) * scale;
        if (relu) x = fmaxf(x, 0.f);
        v[r] = x;
      }
      if (Cb) {
        u16x4 u;
#pragma unroll
        for (int r = 0; r < 4; r++) {
          bf16 tb = __float2bfloat16(v[r]);
          u[r] = *(unsigned short*)&tb;
        }
        *(u16x4*)(Cb + rb + colb) = u;
      } else {
        *(f32x4*)(Cf + rb + colb) = v;
      }
    }
  }
}

// ---------------------------------------------------------------------------
// Attention: one block (4 waves) per (h, b). Wave w owns q-tiles 2w, 2w+1.
// M=2048 in 64-row chunks, DOUBLE-BUFFERED LDS staging (K natural [64][32];
// V transposed [32][72]); issue next chunk's global loads before compute,
// write to the other buffer after, single barrier per iteration.
// kv layout: [b*2048 rows][1024], layer at col offset loff (K at +0, V at +256).
// ---------------------------------------------------------------------------
__global__ __launch_bounds__(256) void attn_kernel(
    const bf16* __restrict__ q, const bf16* __restrict__ kv, bf16* __restrict__ wv,
    int loff) {
  const int h = blockIdx.x;   // 0..7
  const int b = blockIdx.y;   // 0..63
  const int t = threadIdx.x;
  const int w = t >> 6, lane = t & 63;
  const int l15 = lane & 15, quad = lane >> 4;

  __shared__ bf16 Kls[2][64 * 32];
  __shared__ bf16 Vtls[2][32 * 72];
  __shared__ bf16 Pls[4][16 * 72];

  s16x8 aQ[2];
  f32x4 zero4 = {0.f, 0.f, 0.f, 0.f};
  f32x4 o[2][2];
  float lsum[2][4];
#pragma unroll
  for (int i = 0; i < 2; i++) {
    o[i][0] = zero4; o[i][1] = zero4;
#pragma unroll
    for (int r = 0; r < 4; r++) lsum[i][r] = 0.f;
  }
#pragma unroll
  for (int qt = 0; qt < 2; qt++) {
    const int row = (2 * w + qt) * 16 + l15;
    s16x8 tmp = {0, 0, 0, 0, 0, 0, 0, 0};
    if (row < 100)
      tmp = *(const s16x8*)(q + ((long)(b * 100 + row)) * 256 + h * 32 + quad * 8);
    aQ[qt] = tmp;
  }

  const bf16* kvb = kv + (long)b * 2048 * 1024 + loff;
  const int sr = t >> 2, ss = t & 3;

  {  // prologue: stage chunk 0 into buffer 0
    const uint4 gk = *(const uint4*)(kvb + (long)sr * 1024 + h * 32 + ss * 8);
    *(uint4*)(&Kls[0][sr * 32 + ss * 8]) = gk;
    const uint4 gv = *(const uint4*)(kvb + (long)sr * 1024 + 256 + h * 32 + ss * 8);
    const bf16* vs = (const bf16*)&gv;
#pragma unroll
    for (int j = 0; j < 8; j++) Vtls[0][(ss * 8 + j) * 72 + sr] = vs[j];
  }
  __syncthreads();

  int cur = 0;
  for (int mc = 0; mc < 2048; mc += 64) {
    uint4 gk, gv;
    const bool more = (mc + 64) < 2048;
    if (more) {
      gk = *(const uint4*)(kvb + (long)(mc + 64 + sr) * 1024 + h * 32 + ss * 8);
      gv = *(const uint4*)(kvb + (long)(mc + 64 + sr) * 1024 + 256 + h * 32 + ss * 8);
    }

    s16x8 bk[4], bv00, bv01, bv10, bv11;
#pragma unroll
    for (int f = 0; f < 4; f++)
      bk[f] = *(const s16x8*)(&Kls[cur][(f * 16 + l15) * 32 + quad * 8]);
    bv00 = *(const s16x8*)(&Vtls[cur][l15 * 72 + quad * 8]);
    bv01 = *(const s16x8*)(&Vtls[cur][l15 * 72 + 32 + quad * 8]);
    bv10 = *(const s16x8*)(&Vtls[cur][(16 + l15) * 72 + quad * 8]);
    bv11 = *(const s16x8*)(&Vtls[cur][(16 + l15) * 72 + 32 + quad * 8]);

#pragma unroll
    for (int qt = 0; qt < 2; qt++) {
      f32x4 s_[4];
#pragma unroll
      for (int f = 0; f < 4; f++)
        s_[f] = __builtin_amdgcn_mfma_f32_16x16x32_bf16(aQ[qt], bk[f], zero4, 0, 0, 0);
#pragma unroll
      for (int f = 0; f < 4; f++) {
#pragma unroll
        for (int r = 0; r < 4; r++) {
          const float pv = __expf(s_[f][r]);
          lsum[qt][r] += pv;
          Pls[w][(quad * 4 + r) * 72 + f * 16 + l15] = __float2bfloat16(pv);
        }
      }
      __threadfence_block();
      const s16x8 aP0 = *(const s16x8*)(&Pls[w][0] + l15 * 72 + quad * 8);
      const s16x8 aP1 = *(const s16x8*)(&Pls[w][0] + l15 * 72 + 32 + quad * 8);
      o[qt][0] = __builtin_amdgcn_mfma_f32_16x16x32_bf16(aP0, bv00, o[qt][0], 0, 0, 0);
      o[qt][0] = __builtin_amdgcn_mfma_f32_16x16x32_bf16(aP1, bv01, o[qt][0], 0, 0, 0);
      o[qt][1] = __builtin_amdgcn_mfma_f32_16x16x32_bf16(aP0, bv10, o[qt][1], 0, 0, 0);
      o[qt][1] = __builtin_amdgcn_mfma_f32_16x16x32_bf16(aP1, bv11, o[qt][1], 0, 0, 0);
    }

    if (more) {
      *(uint4*)(&Kls[cur ^ 1][sr * 32 + ss * 8]) = gk;
      const bf16* vs = (const bf16*)&gv;
#pragma unroll
      for (int j = 0; j < 8; j++) Vtls[cur ^ 1][(ss * 8 + j) * 72 + sr] = vs[j];
    }
    __syncthreads();
    cur ^= 1;
  }

#pragma unroll
  for (int qt = 0; qt < 2; qt++) {
    const int gq = (2 * w + qt) * 16;
#pragma unroll
    for (int r = 0; r < 4; r++) {
      float l = lsum[qt][r];
      l += __shfl_xor(l, 1); l += __shfl_xor(l, 2);
      l += __shfl_xor(l, 4); l += __shfl_xor(l, 8);
      const float inv = 1.f / l;
      const int qrow = gq + quad * 4 + r;
      if (qrow < 100) {
        const long base = ((long)(b * 100 + qrow)) * 256 + h * 32;
        wv[base + l15]      = __float2bfloat16(o[qt][0][r] * inv);
        wv[base + 16 + l15] = __float2bfloat16(o[qt][1][r] * inv);
      }
    }
  }
}

// ---------------------------------------------------------------------------
// Residual + LayerNorm (fp32): z = LN(z + d)*g + be; also bf16 copy.
// ---------------------------------------------------------------------------
__global__ __launch_bounds__(64) void ln_kernel(
    float* __restrict__ z, const float* __restrict__ d,
    const float* __restrict__ g, const float* __restrict__ be, bf16* __restrict__ zb) {
  const int row = blockIdx.x, t = threadIdx.x;
  float4 x = *(const float4*)(z + (long)row * 256 + t * 4);
  const float4 dd = *(const float4*)(d + (long)row * 256 + t * 4);
  x.x += dd.x; x.y += dd.y; x.z += dd.z; x.w += dd.w;
  float s1 = x.x + x.y + x.z + x.w;
  float s2 = x.x * x.x + x.y * x.y + x.z * x.z + x.w * x.w;
#pragma unroll
  for (int m = 1; m < 64; m <<= 1) {
    s1 += __shfl_xor(s1, m);
    s2 += __shfl_xor(s2, m);
  }
  const float mu = s1 * (1.f / 256.f);
  const float var = s2 * (1.f / 256.f) - mu * mu;
  const float rs = rsqrtf(var + 1e-5f);
  const float4 gg = *(const float4*)(g + t * 4);
  const float4 bb = *(const float4*)(be + t * 4);
  float4 y;
  y.x = (x.x - mu) * rs * gg.x + bb.x;
  y.y = (x.y - mu) * rs * gg.y + bb.y;
  y.z = (x.z - mu) * rs * gg.z + bb.z;
  y.w = (x.w - mu) * rs * gg.w + bb.w;
  *(float4*)(z + (long)row * 256 + t * 4) = y;
  bf16* zo = zb + (long)row * 256 + t * 4;
  zo[0] = __float2bfloat16(y.x); zo[1] = __float2bfloat16(y.y);
  zo[2] = __float2bfloat16(y.z); zo[3] = __float2bfloat16(y.w);
}

// out[n,c,s] = features[n,c,s] + zp[n,c]  (float4, z-row cached in LDS)
__global__ __launch_bounds__(256) void final_add(
    const float* __restrict__ feat, const float* __restrict__ zp, float* __restrict__ out) {
  __shared__ float zs[256];
  const int n = blockIdx.x, t = threadIdx.x;
  zs[t] = zp[n * 256 + t];
  __syncthreads();
  const f32x4* f4 = (const f32x4*)(feat + (long)n * 12544);
  f32x4* o4 = (f32x4*)(out + (long)n * 12544);
#pragma unroll
  for (int i = 0; i < 12; i++) {
    const int e = i * 256 + t;
    f32x4 v = f4[e];
    const int g = e * 4;
    v[0] += zs[g / 49]; v[1] += zs[(g + 1) / 49];
    v[2] += zs[(g + 2) / 49]; v[3] += zs[(g + 3) / 49];
    o4[e] = v;
  }
  if (t < 64) {
    const int e = 3072 + t;
    f32x4 v = f4[e];
    const int g = e * 4;
    v[0] += zs[g / 49]; v[1] += zs[(g + 1) / 49];
    v[2] += zs[(g + 2) / 49]; v[3] += zs[(g + 3) / 49];
    o4[e] = v;
  }
}

// ---------------------------------------------------------------------------
extern "C" void kernel_launch(void* const* d_in, const int* in_sizes, int n_in,
                              void* d_out, int out_size, void* d_ws, size_t ws_size,
                              hipStream_t stream) {
  (void)in_sizes; (void)n_in; (void)out_size; (void)ws_size;
  const float* features = (const float*)d_in[0];
  const float* memory_  = (const float*)d_in[1];
  const float* Wq_  = (const float*)d_in[2];
  const float* bq_  = (const float*)d_in[3];
  const float* Wk_  = (const float*)d_in[4];
  const float* bk_  = (const float*)d_in[5];
  const float* Wv_  = (const float*)d_in[6];
  const float* bv_  = (const float*)d_in[7];
  const float* Wf_  = (const float*)d_in[8];
  const float* bf_  = (const float*)d_in[9];
  const float* g1_  = (const float*)d_in[10];
  const float* be1_ = (const float*)d_in[11];
  const float* g2_  = (const float*)d_in[12];
  const float* be2_ = (const float*)d_in[13];
  const float* W1_  = (const float*)d_in[14];
  const float* b1_  = (const float*)d_in[15];
  const float* W2_  = (const float*)d_in[16];
  const float* b2_  = (const float*)d_in[17];
  const float* Wp1_ = (const float*)d_in[18];
  const float* bp1_ = (const float*)d_in[19];
  const float* Wp2_ = (const float*)d_in[20];
  const float* bp2_ = (const float*)d_in[21];
  float* out = (float*)d_out;

  char* p = (char*)d_ws;
  auto alloc = [&](size_t bytes) {
    char* r = p;
    p += (bytes + 255) & ~(size_t)255;
    return r;
  };
  float* z     = (float*)alloc((size_t)6400 * 256 * 4);
  float* fb    = (float*)alloc((size_t)6400 * 256 * 4);
  bf16*  zb    = (bf16*)alloc((size_t)6400 * 256 * 2);
  bf16*  qb    = (bf16*)alloc((size_t)6400 * 256 * 2);
  bf16*  wvb   = (bf16*)alloc((size_t)6400 * 256 * 2);
  bf16*  hb    = (bf16*)alloc((size_t)6400 * 1024 * 2);
  bf16*  memb  = (bf16*)alloc((size_t)131072 * 288 * 2);
  bf16*  kvbuf = (bf16*)alloc((size_t)131072 * 1024 * 2);  // both layers, ld=1024
  bf16*  wkvT  = (bf16*)alloc((size_t)2 * 512 * 288 * 2);  // = [1024][288]
  bf16*  wqT   = (bf16*)alloc((size_t)2 * 256 * 256 * 2);
  bf16*  wfT   = (bf16*)alloc((size_t)2 * 256 * 256 * 2);
  bf16*  w1T   = (bf16*)alloc((size_t)2 * 1024 * 256 * 2);
  bf16*  w2T   = (bf16*)alloc((size_t)2 * 256 * 1024 * 2);
  bf16*  wp1T  = (bf16*)alloc((size_t)1024 * 256 * 2);
  bf16*  wp2T  = (bf16*)alloc((size_t)256 * 1024 * 2);
  float* kvbias = (float*)alloc((size_t)1024 * 4);

  // all conversions/transposes/bias-concat in one launch
  prep_kernel<<<MEM_BLKS + PAD_BLKS + 5889, 256, 0, stream>>>(
      memory_, memb, Wq_, Wk_, Wv_, Wf_, W1_, W2_, Wp1_, Wp2_, bk_, bv_,
      wqT, wkvT, wfT, w1T, w2T, wp1T, wp2T, kvbias);

  pool_kernel<<<6400, 256, 0, stream>>>(features, z, zb);

  // K|V projection for BOTH layers in one GEMM:
  // [131072,288] x [288,1024] -> bf16 [131072,1024]
  gemm_bt<<<dim3(1024, 8), 256, 0, stream>>>(memb, wkvT, kvbias,
      nullptr, kvbuf, 288, 288, 288, 1024, 1.f, 0);

  for (int l = 0; l < 2; l++) {
    // Q projection (pre-scaled by SCALER)
    gemm_bt<<<dim3(50, 2), 256, 0, stream>>>(zb, wqT + (long)l * 65536,
        bq_ + l * 256, nullptr, qb, 256, 256, 256, 256, SCALER_F, 0);
    attn_kernel<<<dim3(8, 64), 256, 0, stream>>>(qb, kvbuf, wvb, l * 512);
    // f = wv @ Wf + bf (fp32)
    gemm_bt<<<dim3(50, 2), 256, 0, stream>>>(wvb, wfT + (long)l * 65536,
        bf_ + l * 256, fb, nullptr, 256, 256, 256, 256, 1.f, 0);
    ln_kernel<<<6400, 64, 0, stream>>>(z, fb, g1_ + l * 256, be1_ + l * 256, zb);
    // FF
    gemm_bt<<<dim3(50, 8), 256, 0, stream>>>(zb, w1T + (long)l * 262144,
        b1_ + l * 1024, nullptr, hb, 256, 256, 256, 1024, 1.f, 1);
    gemm_bt<<<dim3(50, 2), 256, 0, stream>>>(hb, w2T + (long)l * 262144,
        b2_ + l * 256, fb, nullptr, 1024, 1024, 1024, 256, 1.f, 0);
    ln_kernel<<<6400, 64, 0, stream>>>(z, fb, g2_ + l * 256, be2_ + l * 256, zb);
  }

  // ff_post
  gemm_bt<<<dim3(50, 8), 256, 0, stream>>>(zb, wp1T, bp1_, nullptr, hb,
      256, 256, 256, 1024, 1.f, 1);
  gemm_bt<<<dim3(50, 2), 256, 0, stream>>>(hb, wp2T, bp2_, fb,
      nullptr, 1024, 1024, 1024, 256, 1.f, 0);

  final_add<<<6400, 256, 0, stream>>>(features, fb, out);
}